// Round 12
// baseline (346.234 us; speedup 1.0000x reference)
//
#include <hip/hip_runtime.h>
#include <stdint.h>

typedef unsigned short ushort_t;
typedef unsigned int uint32;

typedef __attribute__((ext_vector_type(8))) short short8;
typedef __attribute__((ext_vector_type(4))) float floatx4;
typedef __attribute__((ext_vector_type(2))) float float2v;
typedef __attribute__((ext_vector_type(4))) uint32 uint4v;

#define NEG_SLOPE 0.2f

__device__ __forceinline__ ushort_t f2bf(float f) {
    union { float f; uint32 u; } v; v.f = f;
    uint32 u = v.u;
    uint32 r = (u + 0x7fffu + ((u >> 16) & 1u)) >> 16;
    return (ushort_t)r;
}
__device__ __forceinline__ float2 bf2x(uint32 u) {
    union { uint32 u; float f; } a, b;
    a.u = u << 16; b.u = u & 0xffff0000u;
    float2 r; r.x = a.f; r.y = b.f; return r;
}

// Per-wave exclusive prefix of bsum[0..nb): lane i ends holding excl(i).
// All shuffles full-wave (R8 lesson: ds_bpermute sources must be active).
__device__ __forceinline__ int bsum_excl_scan(const int* __restrict__ bsum,
                                              int nb, int lane) {
    int v = (lane < nb) ? bsum[lane] : 0;
    int orig = v;
    #pragma unroll
    for (int off = 1; off < 64; off <<= 1) {
        int u = __shfl(v, (lane - off) & 63);
        if (lane >= off) v += u;
    }
    return v - orig;   // exclusive prefix at this lane
}

// ---------------- dtype sniffer (block 0) | cnt zeroing (blocks 1..nb) ----------------
__global__ void k_sniff(const uint32* __restrict__ x, int* __restrict__ flag,
                        int* __restrict__ cnt) {
    if (blockIdx.x == 0) {
        __shared__ int sh[256];
        int t = threadIdx.x;
        int c = 0;
        for (int i = t; i < 1024; i += 256) {
            uint32 h = x[i] & 0xFFFFu;
            uint32 e = (h >> 7) & 0xFFu;
            if (h == 0u || (e >= 100u && e <= 140u)) c++;
        }
        sh[t] = c; __syncthreads();
        for (int off = 128; off >= 1; off >>= 1) {
            if (t < off) sh[t] += sh[t + off];
            __syncthreads();
        }
        if (t == 0) flag[0] = (sh[0] >= 512) ? 1 : 0;
    } else {
        // zero 1024 ints per block (allocation is padded; writes past N are harmless)
        int i = ((blockIdx.x - 1) * 256 + threadIdx.x) * 4;
        int4 z = {0, 0, 0, 0};
        *(int4*)(cnt + i) = z;
    }
}

// ---------------- GEMM body (shared by fused layer-0 kernel and k_gemm) ----------------
__device__ __forceinline__ void gemm_body(int bid, int tid,
                                          const void* __restrict__ actv,
                                          const ushort_t* __restrict__ W,
                                          ushort_t* __restrict__ hb,
                                          float* __restrict__ als,
                                          float* __restrict__ ald,
                                          const ushort_t* __restrict__ asrcp,
                                          const ushort_t* __restrict__ adstp,
                                          int N, int layer0,
                                          const int* __restrict__ flag) {
    int wid = tid >> 6, lane = tid & 63;
    int n0 = (bid * 4 + wid) * 16;
    int mrow = lane & 15, quad = lane >> 4;
    int n = n0 + mrow;
    bool isf32 = (layer0 && !flag[0]);
    short8 a[4];
    if (n < N) {
        if (isf32) {
            const float* ar = (const float*)actv + (size_t)n * 128 + quad * 8;
            #pragma unroll
            for (int kt = 0; kt < 4; kt++) {
                float4 fa = *(const float4*)(ar + kt * 32);
                float4 fb = *(const float4*)(ar + kt * 32 + 4);
                short8 v;
                v[0] = (short)f2bf(fa.x); v[1] = (short)f2bf(fa.y);
                v[2] = (short)f2bf(fa.z); v[3] = (short)f2bf(fa.w);
                v[4] = (short)f2bf(fb.x); v[5] = (short)f2bf(fb.y);
                v[6] = (short)f2bf(fb.z); v[7] = (short)f2bf(fb.w);
                a[kt] = v;
            }
        } else {
            const ushort_t* ar = (const ushort_t*)actv + (size_t)n * 128 + quad * 8;
            #pragma unroll
            for (int kt = 0; kt < 4; kt++) a[kt] = *(const short8*)(ar + kt * 32);
        }
    } else {
        #pragma unroll
        for (int kt = 0; kt < 4; kt++) { short8 z = {0,0,0,0,0,0,0,0}; a[kt] = z; }
    }
    float ps[4], pd[4];
    #pragma unroll
    for (int t = 0; t < 8; t++) {
        if ((t & 1) == 0) {
            #pragma unroll
            for (int r = 0; r < 4; r++) { ps[r] = 0.f; pd[r] = 0.f; }
        }
        const ushort_t* wr = W + (size_t)(t * 16 + mrow) * 128 + quad * 8;
        floatx4 acc = {0.f, 0.f, 0.f, 0.f};
        #pragma unroll
        for (int kt = 0; kt < 4; kt++) {
            short8 b = *(const short8*)(wr + kt * 32);
            acc = __builtin_amdgcn_mfma_f32_16x16x32_bf16(a[kt], b, acc, 0, 0, 0);
        }
        int col = t * 16 + mrow;
        union { uint32 u; float f; } cs, cd;
        cs.u = ((uint32)asrcp[col]) << 16;
        cd.u = ((uint32)adstp[col]) << 16;
        #pragma unroll
        for (int r = 0; r < 4; r++) {
            int rn = n0 + quad * 4 + r;
            if (rn < N) hb[(size_t)rn * 128 + col] = f2bf(acc[r]);
            ps[r] += acc[r] * cs.f;
            pd[r] += acc[r] * cd.f;
        }
        if (t & 1) {
            #pragma unroll
            for (int off = 1; off <= 8; off <<= 1) {
                #pragma unroll
                for (int r = 0; r < 4; r++) {
                    ps[r] += __shfl_xor(ps[r], off);
                    pd[r] += __shfl_xor(pd[r], off);
                }
            }
            int h = t >> 1;
            if (mrow < 8) {
                int r = mrow & 3;
                float vs = r == 0 ? ps[0] : r == 1 ? ps[1] : r == 2 ? ps[2] : ps[3];
                float vd = r == 0 ? pd[0] : r == 1 ? pd[1] : r == 2 ? pd[2] : pd[3];
                int rn = n0 + quad * 4 + r;
                if (rn < N) {
                    float* dp = (mrow < 4) ? als : ald;
                    dp[(size_t)rn * 4 + h] = (mrow < 4) ? vs : vd;
                }
            }
        }
    }
}

__global__ __launch_bounds__(256) void k_gemm(const void* __restrict__ actv,
                                              const ushort_t* __restrict__ W,
                                              ushort_t* __restrict__ hb,
                                              float* __restrict__ als,
                                              float* __restrict__ ald,
                                              const ushort_t* __restrict__ asrcp,
                                              const ushort_t* __restrict__ adstp,
                                              int N, const int* __restrict__ flag) {
    gemm_body(blockIdx.x, threadIdx.x, actv, W, hb, als, ald, asrcp, adstp, N, 0, flag);
}

// ---------------- fused: param canonicalization (197 blocks) | hist x4-unrolled (rest) ----------------
__global__ void k_f1(const void* W0, const void* W1, const void* W2,
                     const void* s0, const void* s1, const void* s2,
                     const void* a0, const void* a1, const void* a2,
                     const void* b0, const void* b1, const void* b2,
                     ushort_t* __restrict__ pblk, const int* __restrict__ flag,
                     const int* __restrict__ dst, int* __restrict__ cnt,
                     int* __restrict__ rank, int E) {
    if (blockIdx.x < 197) {
        int i = blockIdx.x * 256 + threadIdx.x;
        if (i >= 50304) return;
        const void* src; int off;
        if (i < 49152) {
            int seg = i / 16384; off = i % 16384;
            src = seg == 0 ? W0 : seg == 1 ? W1 : W2;
        } else if (i < 49536) {
            int j = i - 49152; int seg = j / 128; off = j % 128;
            src = seg == 0 ? s0 : seg == 1 ? s1 : s2;
        } else if (i < 49920) {
            int j = i - 49536; int seg = j / 128; off = j % 128;
            src = seg == 0 ? a0 : seg == 1 ? a1 : a2;
        } else {
            int j = i - 49920; int seg = j / 128; off = j % 128;
            src = seg == 0 ? b0 : seg == 1 ? b1 : b2;
        }
        if (flag[0]) pblk[i] = ((const ushort_t*)src)[off];
        else         pblk[i] = f2bf(((const float*)src)[off]);
    } else {
        // 4 edges per thread: independent atomic chains overlap latency
        int e0 = ((blockIdx.x - 197) * 256 + threadIdx.x) * 4;
        if (e0 + 3 < E) {
            int4 d4 = *(const int4*)(dst + e0);
            int r0 = atomicAdd(&cnt[d4.x], 1);
            int r1 = atomicAdd(&cnt[d4.y], 1);
            int r2 = atomicAdd(&cnt[d4.z], 1);
            int r3 = atomicAdd(&cnt[d4.w], 1);
            int4 r4 = {r0, r1, r2, r3};
            *(int4*)(rank + e0) = r4;
        } else {
            for (int e = e0; e < E; e++) rank[e] = atomicAdd(&cnt[dst[e]], 1);
        }
    }
}

// ---------------- fused: scan_a (nb blocks) | gemm layer-0 (rest) ----------------
// Writes RAW ro (block-local prefix, no cross-block offset) + bsum.
// Consumers reconstruct ro_final[i] = raw[i] + excl_bsum[(i-1)>>10] in-register
// (k_scan_bc dispatch eliminated).
__global__ __launch_bounds__(256) void k_f2(const int* __restrict__ cnt, int* __restrict__ ro,
                                            int* __restrict__ bsum, int n, int nb,
                                            const void* __restrict__ actv,
                                            const ushort_t* __restrict__ W,
                                            ushort_t* __restrict__ hb,
                                            float* __restrict__ als, float* __restrict__ ald,
                                            const ushort_t* __restrict__ asrcp,
                                            const ushort_t* __restrict__ adstp,
                                            int N, const int* __restrict__ flag) {
    if ((int)blockIdx.x < nb) {
        __shared__ int sd[256];
        int t = threadIdx.x;
        int base = blockIdx.x * 1024 + t * 4;
        int v0 = (base + 0 < n) ? cnt[base + 0] : 0;
        int v1 = (base + 1 < n) ? cnt[base + 1] : 0;
        int v2 = (base + 2 < n) ? cnt[base + 2] : 0;
        int v3 = (base + 3 < n) ? cnt[base + 3] : 0;
        int s = v0 + v1 + v2 + v3;
        sd[t] = s; __syncthreads();
        for (int off = 1; off < 256; off <<= 1) {
            int x = 0;
            if (t >= off) x = sd[t - off];
            __syncthreads();
            sd[t] += x;
            __syncthreads();
        }
        int run = sd[t] - s;
        run += v0; if (base + 0 < n) ro[base + 1] = run;
        run += v1; if (base + 1 < n) ro[base + 2] = run;
        run += v2; if (base + 2 < n) ro[base + 3] = run;
        run += v3; if (base + 3 < n) ro[base + 4] = run;
        if (t == 255) bsum[blockIdx.x] = sd[255];
    } else {
        gemm_body(blockIdx.x - nb, threadIdx.x, actv, W, hb, als, ald, asrcp, adstp, N, 1, flag);
    }
}

// atomic-free scatter; u16 node indices (requires N < 65536); x4 unrolled.
// ro offsets resolved in-register via per-wave bsum scan + variable-index shfl.
// DIVERGENCE DISCIPLINE (R10 bug): the full/tail split is NOT wave-uniform in
// the last block. All __shfl calls (bsum scan + ro_at) execute full-wave,
// unconditionally; only the loads/stores are predicated.
__global__ __launch_bounds__(256) void k_scatter(const int* __restrict__ src,
                          const int* __restrict__ dst,
                          const int* __restrict__ ro, const int* __restrict__ rank,
                          const int* __restrict__ bsum, int nb,
                          ushort_t* __restrict__ ssrc, int E) {
    int lane = threadIdx.x & 63;
    int excl = bsum_excl_scan(bsum, nb, lane);   // lane i holds excl(i)

    int e0 = (blockIdx.x * 256 + threadIdx.x) * 4;
    int d0 = 0, d1 = 0, d2 = 0, d3 = 0;
    int s0 = 0, s1 = 0, s2 = 0, s3 = 0;
    int q0 = 0, q1 = 0, q2 = 0, q3 = 0;
    if (e0 + 3 < E) {
        int4 d4 = *(const int4*)(dst + e0);
        int4 s4 = *(const int4*)(src + e0);
        int4 r4 = *(const int4*)(rank + e0);
        d0 = d4.x; d1 = d4.y; d2 = d4.z; d3 = d4.w;
        s0 = s4.x; s1 = s4.y; s2 = s4.z; s3 = s4.w;
        q0 = r4.x; q1 = r4.y; q2 = r4.z; q3 = r4.w;
    } else {
        if (e0 + 0 < E) { d0 = dst[e0 + 0]; s0 = src[e0 + 0]; q0 = rank[e0 + 0]; }
        if (e0 + 1 < E) { d1 = dst[e0 + 1]; s1 = src[e0 + 1]; q1 = rank[e0 + 1]; }
        if (e0 + 2 < E) { d2 = dst[e0 + 2]; s2 = src[e0 + 2]; q2 = rank[e0 + 2]; }
    }
    // full-wave offset resolution (every lane executes all four shuffles)
    int p0 = __shfl(excl, ((d0 - 1) >> 10) & 63);
    int p1 = __shfl(excl, ((d1 - 1) >> 10) & 63);
    int p2 = __shfl(excl, ((d2 - 1) >> 10) & 63);
    int p3 = __shfl(excl, ((d3 - 1) >> 10) & 63);
    int b0 = (d0 == 0) ? 0 : ro[d0] + p0;
    int b1 = (d1 == 0) ? 0 : ro[d1] + p1;
    int b2 = (d2 == 0) ? 0 : ro[d2] + p2;
    int b3 = (d3 == 0) ? 0 : ro[d3] + p3;
    if (e0 + 0 < E) ssrc[b0 + q0] = (ushort_t)s0;
    if (e0 + 1 < E) ssrc[b1 + q1] = (ushort_t)s1;
    if (e0 + 2 < E) ssrc[b2 + q2] = (ushort_t)s2;
    if (e0 + 3 < E) ssrc[b3 + q3] = (ushort_t)s3;
}

// ---------------- softmax + aggregation ----------------
// 4 waves / block, one NODE per wave, fully in-register (no LDS, no barriers).
// The wave preloads up to 64 edge sources with ONE u16 wave-load, then each
// 16-lane group gets its edge via __shfl (1 VALU op) instead of a per-iteration
// VMEM load. ro offsets resolved via per-wave bsum scan (k_scan_bc eliminated).
// CORRECTNESS NOTE: __shfl lowers to ds_bpermute; source lanes must be active.
// All shuffles here execute full-wave; only edge_step is predicated. The n>=N
// early-return is wave-uniform (wid constant per wave; gagg*4==N anyway).
__global__ __launch_bounds__(256) void k_agg(const int* __restrict__ ro,
                                             const int* __restrict__ bsum, int nb,
                                             const ushort_t* __restrict__ ssrc,
                                             const ushort_t* __restrict__ hb,
                                             const float* __restrict__ als,
                                             const float* __restrict__ ald_,
                                             const ushort_t* __restrict__ bias,
                                             void* __restrict__ outp, int N, int apply_elu,
                                             int is_final, const int* __restrict__ flag) {
    int wid = threadIdx.x >> 6;
    int lane = threadIdx.x & 63;
    int n = blockIdx.x * 4 + wid;
    if (n >= N) return;   // wave-uniform (wid constant across the wave)

    int excl = bsum_excl_scan(bsum, nb, lane);   // lane i holds excl(i)
    int pre0 = __shfl(excl, ((n - 1) >> 10) & 63);
    int pre1 = __shfl(excl, (n >> 10) & 63);
    int r0 = (n == 0) ? 0 : ro[n] + pre0;
    int r1 = ro[n + 1] + pre1;
    int deg = r1 - r0;

    int grp = lane >> 4;      // which edge within a quad of edges
    int sub = lane & 15;      // channel block: owns channels [sub*8, sub*8+8)
    int hd = sub >> 2;        // head of owned channels

    float adh = ald_[(size_t)n * 4 + hd];
    const char* alsb = (const char*)als;
    const char* hbb = (const char*)hb;
    int hoff = hd << 2;       // byte offset of my head's als scalar within a row
    int coff = sub << 4;      // byte offset of my 16B channel block within a row

    float2v acc2[4];
    #pragma unroll
    for (int k = 0; k < 4; k++) { float2v z = {0.f, 0.f}; acc2[k] = z; }
    float d = 0.f;

    auto edge_step = [&](int s) {
        float asv = *(const float*)(alsb + ((uint32)s << 4) + hoff);
        float tv = asv + adh;
        float w = __expf(fmaxf(tv, NEG_SLOPE * tv));
        d += w;
        uint4v hv = *(const uint4v*)(hbb + ((uint32)s << 8) + coff);
        #pragma unroll
        for (int k = 0; k < 4; k++) {
            float2 p = bf2x(hv[k]);
            float2v pv = {p.x, p.y};
            acc2[k] += w * pv;
        }
    };

    for (int base = 0; base < deg; base += 64) {
        int cend = min(deg - base, 64);
        // one coalesced wave-load covers the whole chunk's edge list
        int sv = 0;
        if (lane < cend) sv = ssrc[r0 + base + lane];
        int nfull = cend >> 2;
        #pragma unroll 4
        for (int t = 0; t < nfull; t++) {
            int s = __shfl(sv, t * 4 + grp);   // full-wave shuffle: every slot published
            edge_step(s);
        }
        int ti = nfull * 4 + grp;
        // full-wave shuffle OUTSIDE the predicate (ds_bpermute from an inactive
        // lane is undefined); &63 keeps index legal when cend==64 (tail is dead).
        int s = __shfl(sv, ti & 63);
        if (ti < cend) edge_step(s);
    }
    // fold the 4 edge-groups: lanes {sub, sub+16, sub+32, sub+48} hold the same channels
    #pragma unroll
    for (int k = 0; k < 4; k++) {
        acc2[k].x += __shfl_xor(acc2[k].x, 16);
        acc2[k].y += __shfl_xor(acc2[k].y, 16);
        acc2[k].x += __shfl_xor(acc2[k].x, 32);
        acc2[k].y += __shfl_xor(acc2[k].y, 32);
    }
    // denominator: same fold (each lane's d covers its group's edges, own head)
    d += __shfl_xor(d, 16);
    d += __shfl_xor(d, 32);

    if (grp == 0) {
        float inv = 1.0f / (d + 1e-16f);
        int c0 = sub << 3;
        short8 bv8 = *(const short8*)(bias + c0);
        float o[8];
        #pragma unroll
        for (int k = 0; k < 4; k++) {
            union { uint32 u; float f; } blo, bhi;
            blo.u = ((uint32)(ushort_t)bv8[2 * k]) << 16;
            bhi.u = ((uint32)(ushort_t)bv8[2 * k + 1]) << 16;
            o[2 * k]     = acc2[k].x * inv + blo.f;
            o[2 * k + 1] = acc2[k].y * inv + bhi.f;
        }
        if (apply_elu) {
            #pragma unroll
            for (int k = 0; k < 8; k++)
                o[k] = o[k] > 0.f ? o[k] : __expf(o[k]) - 1.f;  // |err| below bf16 rounding
        }
        if (is_final && !flag[0]) {
            float* op = (float*)outp + (size_t)n * 128 + c0;
            float4 lo = {o[0], o[1], o[2], o[3]};
            float4 hi = {o[4], o[5], o[6], o[7]};
            *(float4*)op = lo;
            *(float4*)(op + 4) = hi;
        } else {
            short8 pk;
            #pragma unroll
            for (int k = 0; k < 8; k++) pk[k] = (short)f2bf(o[k]);
            *(short8*)((ushort_t*)outp + (size_t)n * 128 + c0) = pk;
        }
    }
}

extern "C" void kernel_launch(void* const* d_in, const int* in_sizes, int n_in,
                              void* d_out, int out_size, void* d_ws, size_t ws_size,
                              hipStream_t stream) {
    const void* x = d_in[0];
    const int* src = (const int*)d_in[1];
    const int* dst = (const int*)d_in[2];
    const int N = in_sizes[0] / 128;   // 50000 (< 65536 required for u16 ssrc)
    const int E = in_sizes[1];

    char* p = (char*)d_ws;
    auto alloc = [&](size_t bytes) { char* r = p; p += (bytes + 255) & ~(size_t)255; return r; };
    int*      flag  = (int*)alloc(256);
    int*      bsum  = (int*)alloc(256 * 4);
    int*      ro    = (int*)alloc((size_t)(N + 1) * 4);
    ushort_t* ssrc  = (ushort_t*)alloc((size_t)E * 2);         // also aliases cnt (int[N]) early
    ushort_t* hb    = (ushort_t*)alloc((size_t)N * 128 * 2);
    float*    als   = (float*)alloc((size_t)N * 4 * 4);
    float*    ald   = (float*)alloc((size_t)N * 4 * 4);
    ushort_t* xact  = (ushort_t*)alloc((size_t)N * 128 * 2);   // also aliases rank (int[E]) early
    ushort_t* pblk  = (ushort_t*)alloc((size_t)50304 * 2);

    int* cnt  = (int*)ssrc;    // dead once scatter overwrites ssrc
    int* rank = (int*)xact;    // dead once agg0 writes xact

    int g256e4 = (E + 1023) / 1024;
    int nb = (N + 1023) / 1024;   // 49 (<= 64 required by wave-scan)
    int gg = (N + 63) / 64;
    int gagg = (N + 3) / 4;

    // block 0: dtype sniff; blocks 1..nb: zero cnt (replaces hipMemsetAsync launch)
    k_sniff<<<1 + nb, 256, 0, stream>>>((const uint32*)x, flag, cnt);
    k_f1<<<197 + g256e4, 256, 0, stream>>>(
        d_in[3], d_in[7], d_in[11],
        d_in[4], d_in[8], d_in[12],
        d_in[5], d_in[9], d_in[13],
        d_in[6], d_in[10], d_in[14],
        pblk, flag, dst, cnt, rank, E);
    k_f2<<<nb + gg, 256, 0, stream>>>(cnt, ro, bsum, N, nb,
        x, pblk, hb, als, ald, pblk + 49152, pblk + 49536, N, flag);
    k_scatter<<<g256e4, 256, 0, stream>>>(src, dst, ro, rank, bsum, nb, ssrc, E);

    for (int l = 0; l < 3; l++) {
        const ushort_t* As = pblk + 49152 + l * 128;
        const ushort_t* Ad = pblk + 49536 + l * 128;
        const ushort_t* Bc = pblk + 49920 + l * 128;
        void* outp = (l == 2) ? d_out : (void*)xact;
        if (l > 0) {
            const ushort_t* Wc = pblk + (size_t)l * 16384;
            k_gemm<<<gg, 256, 0, stream>>>(xact, Wc, hb, als, ald, As, Ad, N, flag);
        }
        k_agg<<<gagg, 256, 0, stream>>>(ro, bsum, nb, ssrc, hb, als, ald, Bc, outp, N,
                                        l < 2 ? 1 : 0, l == 2 ? 1 : 0, flag);
    }
}

// Round 15
// 337.230 us; speedup vs baseline: 1.0267x; 1.0267x over previous
//
#include <hip/hip_runtime.h>
#include <stdint.h>

typedef unsigned short ushort_t;
typedef unsigned int uint32;

typedef __attribute__((ext_vector_type(8))) short short8;
typedef __attribute__((ext_vector_type(4))) float floatx4;
typedef __attribute__((ext_vector_type(2))) float float2v;
typedef __attribute__((ext_vector_type(4))) uint32 uint4v;

#define NEG_SLOPE 0.2f

__device__ __forceinline__ ushort_t f2bf(float f) {
    union { float f; uint32 u; } v; v.f = f;
    uint32 u = v.u;
    uint32 r = (u + 0x7fffu + ((u >> 16) & 1u)) >> 16;
    return (ushort_t)r;
}
__device__ __forceinline__ float2 bf2x(uint32 u) {
    union { uint32 u; float f; } a, b;
    a.u = u << 16; b.u = u & 0xffff0000u;
    float2 r; r.x = a.f; r.y = b.f; return r;
}

// ---------------- dtype sniffer (block 0) | cnt zeroing (blocks 1..nb) ----------------
__global__ void k_sniff(const uint32* __restrict__ x, int* __restrict__ flag,
                        int* __restrict__ cnt) {
    if (blockIdx.x == 0) {
        __shared__ int sh[256];
        int t = threadIdx.x;
        int c = 0;
        for (int i = t; i < 1024; i += 256) {
            uint32 h = x[i] & 0xFFFFu;
            uint32 e = (h >> 7) & 0xFFu;
            if (h == 0u || (e >= 100u && e <= 140u)) c++;
        }
        sh[t] = c; __syncthreads();
        for (int off = 128; off >= 1; off >>= 1) {
            if (t < off) sh[t] += sh[t + off];
            __syncthreads();
        }
        if (t == 0) flag[0] = (sh[0] >= 512) ? 1 : 0;
    } else {
        // zero 1024 ints per block (allocation is padded; writes past N are harmless)
        int i = ((blockIdx.x - 1) * 256 + threadIdx.x) * 4;
        int4 z = {0, 0, 0, 0};
        *(int4*)(cnt + i) = z;
    }
}

// ---------------- GEMM body (shared by fused layer-0 kernel and k_gemm) ----------------
__device__ __forceinline__ void gemm_body(int bid, int tid,
                                          const void* __restrict__ actv,
                                          const ushort_t* __restrict__ W,
                                          ushort_t* __restrict__ hb,
                                          float* __restrict__ als,
                                          float* __restrict__ ald,
                                          const ushort_t* __restrict__ asrcp,
                                          const ushort_t* __restrict__ adstp,
                                          int N, int layer0,
                                          const int* __restrict__ flag) {
    int wid = tid >> 6, lane = tid & 63;
    int n0 = (bid * 4 + wid) * 16;
    int mrow = lane & 15, quad = lane >> 4;
    int n = n0 + mrow;
    bool isf32 = (layer0 && !flag[0]);
    short8 a[4];
    if (n < N) {
        if (isf32) {
            const float* ar = (const float*)actv + (size_t)n * 128 + quad * 8;
            #pragma unroll
            for (int kt = 0; kt < 4; kt++) {
                float4 fa = *(const float4*)(ar + kt * 32);
                float4 fb = *(const float4*)(ar + kt * 32 + 4);
                short8 v;
                v[0] = (short)f2bf(fa.x); v[1] = (short)f2bf(fa.y);
                v[2] = (short)f2bf(fa.z); v[3] = (short)f2bf(fa.w);
                v[4] = (short)f2bf(fb.x); v[5] = (short)f2bf(fb.y);
                v[6] = (short)f2bf(fb.z); v[7] = (short)f2bf(fb.w);
                a[kt] = v;
            }
        } else {
            const ushort_t* ar = (const ushort_t*)actv + (size_t)n * 128 + quad * 8;
            #pragma unroll
            for (int kt = 0; kt < 4; kt++) a[kt] = *(const short8*)(ar + kt * 32);
        }
    } else {
        #pragma unroll
        for (int kt = 0; kt < 4; kt++) { short8 z = {0,0,0,0,0,0,0,0}; a[kt] = z; }
    }
    float ps[4], pd[4];
    #pragma unroll
    for (int t = 0; t < 8; t++) {
        if ((t & 1) == 0) {
            #pragma unroll
            for (int r = 0; r < 4; r++) { ps[r] = 0.f; pd[r] = 0.f; }
        }
        const ushort_t* wr = W + (size_t)(t * 16 + mrow) * 128 + quad * 8;
        floatx4 acc = {0.f, 0.f, 0.f, 0.f};
        #pragma unroll
        for (int kt = 0; kt < 4; kt++) {
            short8 b = *(const short8*)(wr + kt * 32);
            acc = __builtin_amdgcn_mfma_f32_16x16x32_bf16(a[kt], b, acc, 0, 0, 0);
        }
        int col = t * 16 + mrow;
        union { uint32 u; float f; } cs, cd;
        cs.u = ((uint32)asrcp[col]) << 16;
        cd.u = ((uint32)adstp[col]) << 16;
        #pragma unroll
        for (int r = 0; r < 4; r++) {
            int rn = n0 + quad * 4 + r;
            if (rn < N) hb[(size_t)rn * 128 + col] = f2bf(acc[r]);
            ps[r] += acc[r] * cs.f;
            pd[r] += acc[r] * cd.f;
        }
        if (t & 1) {
            #pragma unroll
            for (int off = 1; off <= 8; off <<= 1) {
                #pragma unroll
                for (int r = 0; r < 4; r++) {
                    ps[r] += __shfl_xor(ps[r], off);
                    pd[r] += __shfl_xor(pd[r], off);
                }
            }
            int h = t >> 1;
            if (mrow < 8) {
                int r = mrow & 3;
                float vs = r == 0 ? ps[0] : r == 1 ? ps[1] : r == 2 ? ps[2] : ps[3];
                float vd = r == 0 ? pd[0] : r == 1 ? pd[1] : r == 2 ? pd[2] : pd[3];
                int rn = n0 + quad * 4 + r;
                if (rn < N) {
                    float* dp = (mrow < 4) ? als : ald;
                    dp[(size_t)rn * 4 + h] = (mrow < 4) ? vs : vd;
                }
            }
        }
    }
}

__global__ __launch_bounds__(256) void k_gemm(const void* __restrict__ actv,
                                              const ushort_t* __restrict__ W,
                                              ushort_t* __restrict__ hb,
                                              float* __restrict__ als,
                                              float* __restrict__ ald,
                                              const ushort_t* __restrict__ asrcp,
                                              const ushort_t* __restrict__ adstp,
                                              int N, const int* __restrict__ flag) {
    gemm_body(blockIdx.x, threadIdx.x, actv, W, hb, als, ald, asrcp, adstp, N, 0, flag);
}

// ---------------- fused: param canonicalization (197 blocks) | hist x4-unrolled (rest) ----------------
__global__ void k_f1(const void* W0, const void* W1, const void* W2,
                     const void* s0, const void* s1, const void* s2,
                     const void* a0, const void* a1, const void* a2,
                     const void* b0, const void* b1, const void* b2,
                     ushort_t* __restrict__ pblk, const int* __restrict__ flag,
                     const int* __restrict__ dst, int* __restrict__ cnt,
                     int* __restrict__ rank, int E) {
    if (blockIdx.x < 197) {
        int i = blockIdx.x * 256 + threadIdx.x;
        if (i >= 50304) return;
        const void* src; int off;
        if (i < 49152) {
            int seg = i / 16384; off = i % 16384;
            src = seg == 0 ? W0 : seg == 1 ? W1 : W2;
        } else if (i < 49536) {
            int j = i - 49152; int seg = j / 128; off = j % 128;
            src = seg == 0 ? s0 : seg == 1 ? s1 : s2;
        } else if (i < 49920) {
            int j = i - 49536; int seg = j / 128; off = j % 128;
            src = seg == 0 ? a0 : seg == 1 ? a1 : a2;
        } else {
            int j = i - 49920; int seg = j / 128; off = j % 128;
            src = seg == 0 ? b0 : seg == 1 ? b1 : b2;
        }
        if (flag[0]) pblk[i] = ((const ushort_t*)src)[off];
        else         pblk[i] = f2bf(((const float*)src)[off]);
    } else {
        // 4 edges per thread: independent atomic chains overlap latency
        int e0 = ((blockIdx.x - 197) * 256 + threadIdx.x) * 4;
        if (e0 + 3 < E) {
            int4 d4 = *(const int4*)(dst + e0);
            int r0 = atomicAdd(&cnt[d4.x], 1);
            int r1 = atomicAdd(&cnt[d4.y], 1);
            int r2 = atomicAdd(&cnt[d4.z], 1);
            int r3 = atomicAdd(&cnt[d4.w], 1);
            int4 r4 = {r0, r1, r2, r3};
            *(int4*)(rank + e0) = r4;
        } else {
            for (int e = e0; e < E; e++) rank[e] = atomicAdd(&cnt[dst[e]], 1);
        }
    }
}

// ---------------- fused: scan_a (nb blocks) | gemm layer-0 (rest) ----------------
__global__ __launch_bounds__(256) void k_f2(const int* __restrict__ cnt, int* __restrict__ ro,
                                            int* __restrict__ bsum, int n, int nb,
                                            const void* __restrict__ actv,
                                            const ushort_t* __restrict__ W,
                                            ushort_t* __restrict__ hb,
                                            float* __restrict__ als, float* __restrict__ ald,
                                            const ushort_t* __restrict__ asrcp,
                                            const ushort_t* __restrict__ adstp,
                                            int N, const int* __restrict__ flag) {
    if ((int)blockIdx.x < nb) {
        __shared__ int sd[256];
        int t = threadIdx.x;
        int base = blockIdx.x * 1024 + t * 4;
        int v0 = (base + 0 < n) ? cnt[base + 0] : 0;
        int v1 = (base + 1 < n) ? cnt[base + 1] : 0;
        int v2 = (base + 2 < n) ? cnt[base + 2] : 0;
        int v3 = (base + 3 < n) ? cnt[base + 3] : 0;
        int s = v0 + v1 + v2 + v3;
        sd[t] = s; __syncthreads();
        for (int off = 1; off < 256; off <<= 1) {
            int x = 0;
            if (t >= off) x = sd[t - off];
            __syncthreads();
            sd[t] += x;
            __syncthreads();
        }
        int run = sd[t] - s;
        run += v0; if (base + 0 < n) ro[base + 1] = run;
        run += v1; if (base + 1 < n) ro[base + 2] = run;
        run += v2; if (base + 2 < n) ro[base + 3] = run;
        run += v3; if (base + 3 < n) ro[base + 4] = run;
        if (t == 255) bsum[blockIdx.x] = sd[255];
    } else {
        gemm_body(blockIdx.x - nb, threadIdx.x, actv, W, hb, als, ald, asrcp, adstp, N, 1, flag);
    }
}

// Finalize ro: add cross-block offsets. Prefix of bsum computed by wave 0 via
// shuffle scan (replaces R8's serial 49-iteration thread-0 loop, ~6us -> ~0.5us).
// `t < 64` is wave-uniform (wave 0 fully active) -> shuffles are full-wave safe.
__global__ void k_scan_bc(int* __restrict__ ro, const int* __restrict__ bsum,
                          int n, int nb) {
    __shared__ int pre[64];
    int t = threadIdx.x;
    if (t < 64) {
        int v = (t < nb) ? bsum[t] : 0;
        int orig = v;
        #pragma unroll
        for (int off = 1; off < 64; off <<= 1) {
            int u = __shfl(v, (t - off) & 63);
            if (t >= off) v += u;
        }
        pre[t] = v - orig;   // exclusive prefix
    }
    __syncthreads();
    int i = blockIdx.x * 256 + t;
    if (i == 0) ro[0] = 0;
    if (i < n) ro[i + 1] += pre[i >> 10];
}

// atomic-free scatter; u16 node indices (requires N < 65536); x4 unrolled
__global__ void k_scatter(const int* __restrict__ src, const int* __restrict__ dst,
                          const int* __restrict__ ro, const int* __restrict__ rank,
                          ushort_t* __restrict__ ssrc, int E) {
    int e0 = (blockIdx.x * 256 + threadIdx.x) * 4;
    if (e0 + 3 < E) {
        int4 d4 = *(const int4*)(dst + e0);
        int4 s4 = *(const int4*)(src + e0);
        int4 r4 = *(const int4*)(rank + e0);
        ssrc[ro[d4.x] + r4.x] = (ushort_t)s4.x;
        ssrc[ro[d4.y] + r4.y] = (ushort_t)s4.y;
        ssrc[ro[d4.z] + r4.z] = (ushort_t)s4.z;
        ssrc[ro[d4.w] + r4.w] = (ushort_t)s4.w;
    } else {
        for (int e = e0; e < E; e++) ssrc[ro[dst[e]] + rank[e]] = (ushort_t)src[e];
    }
}

// ---------------- softmax + aggregation ----------------
// 4 waves / block, one NODE per wave, fully in-register (no LDS, no barriers).
// The wave preloads up to 64 edge sources with ONE u16 wave-load, then each
// 16-lane group gets its edge via __shfl (1 VALU op) instead of a per-iteration
// VMEM load, breaking the ssrc->address->gather dependent-load chain.
// CORRECTNESS NOTE: __shfl lowers to ds_bpermute; source lanes must be active.
// All shuffles here execute full-wave; only edge_step is predicated.
__global__ __launch_bounds__(256) void k_agg(const int* __restrict__ ro,
                                             const ushort_t* __restrict__ ssrc,
                                             const ushort_t* __restrict__ hb,
                                             const float* __restrict__ als,
                                             const float* __restrict__ ald_,
                                             const ushort_t* __restrict__ bias,
                                             void* __restrict__ outp, int N, int apply_elu,
                                             int is_final, const int* __restrict__ flag) {
    int wid = threadIdx.x >> 6;
    int lane = threadIdx.x & 63;
    int n = blockIdx.x * 4 + wid;
    if (n >= N) return;   // wave-uniform (wid constant across the wave)

    int r0 = ro[n], r1 = ro[n + 1];
    int deg = r1 - r0;
    int grp = lane >> 4;      // which edge within a quad of edges
    int sub = lane & 15;      // channel block: owns channels [sub*8, sub*8+8)
    int hd = sub >> 2;        // head of owned channels

    float adh = ald_[(size_t)n * 4 + hd];
    const char* alsb = (const char*)als;
    const char* hbb = (const char*)hb;
    int hoff = hd << 2;       // byte offset of my head's als scalar within a row
    int coff = sub << 4;      // byte offset of my 16B channel block within a row

    float2v acc2[4];
    #pragma unroll
    for (int k = 0; k < 4; k++) { float2v z = {0.f, 0.f}; acc2[k] = z; }
    float d = 0.f;

    auto edge_step = [&](int s) {
        float asv = *(const float*)(alsb + ((uint32)s << 4) + hoff);
        float tv = asv + adh;
        float w = __expf(fmaxf(tv, NEG_SLOPE * tv));
        d += w;
        uint4v hv = *(const uint4v*)(hbb + ((uint32)s << 8) + coff);
        #pragma unroll
        for (int k = 0; k < 4; k++) {
            float2 p = bf2x(hv[k]);
            float2v pv = {p.x, p.y};
            acc2[k] += w * pv;
        }
    };

    for (int base = 0; base < deg; base += 64) {
        int cend = min(deg - base, 64);
        // one coalesced wave-load covers the whole chunk's edge list
        int sv = 0;
        if (lane < cend) sv = ssrc[r0 + base + lane];
        int nfull = cend >> 2;
        #pragma unroll 4
        for (int t = 0; t < nfull; t++) {
            int s = __shfl(sv, t * 4 + grp);   // full-wave shuffle: every slot published
            edge_step(s);
        }
        int ti = nfull * 4 + grp;
        // full-wave shuffle OUTSIDE the predicate (ds_bpermute from an inactive
        // lane is undefined); &63 keeps index legal when cend==64 (tail is dead).
        int s = __shfl(sv, ti & 63);
        if (ti < cend) edge_step(s);
    }
    // fold the 4 edge-groups: lanes {sub, sub+16, sub+32, sub+48} hold the same channels
    #pragma unroll
    for (int k = 0; k < 4; k++) {
        acc2[k].x += __shfl_xor(acc2[k].x, 16);
        acc2[k].y += __shfl_xor(acc2[k].y, 16);
        acc2[k].x += __shfl_xor(acc2[k].x, 32);
        acc2[k].y += __shfl_xor(acc2[k].y, 32);
    }
    // denominator: same fold (each lane's d covers its group's edges, own head)
    d += __shfl_xor(d, 16);
    d += __shfl_xor(d, 32);

    if (grp == 0) {
        float inv = 1.0f / (d + 1e-16f);
        int c0 = sub << 3;
        short8 bv8 = *(const short8*)(bias + c0);
        float o[8];
        #pragma unroll
        for (int k = 0; k < 4; k++) {
            union { uint32 u; float f; } blo, bhi;
            blo.u = ((uint32)(ushort_t)bv8[2 * k]) << 16;
            bhi.u = ((uint32)(ushort_t)bv8[2 * k + 1]) << 16;
            o[2 * k]     = acc2[k].x * inv + blo.f;
            o[2 * k + 1] = acc2[k].y * inv + bhi.f;
        }
        if (apply_elu) {
            #pragma unroll
            for (int k = 0; k < 8; k++)
                o[k] = o[k] > 0.f ? o[k] : __expf(o[k]) - 1.f;  // |err| below bf16 rounding
        }
        if (is_final && !flag[0]) {
            float* op = (float*)outp + (size_t)n * 128 + c0;
            float4 lo = {o[0], o[1], o[2], o[3]};
            float4 hi = {o[4], o[5], o[6], o[7]};
            *(float4*)op = lo;
            *(float4*)(op + 4) = hi;
        } else {
            short8 pk;
            #pragma unroll
            for (int k = 0; k < 8; k++) pk[k] = (short)f2bf(o[k]);
            *(short8*)((ushort_t*)outp + (size_t)n * 128 + c0) = pk;
        }
    }
}

extern "C" void kernel_launch(void* const* d_in, const int* in_sizes, int n_in,
                              void* d_out, int out_size, void* d_ws, size_t ws_size,
                              hipStream_t stream) {
    const void* x = d_in[0];
    const int* src = (const int*)d_in[1];
    const int* dst = (const int*)d_in[2];
    const int N = in_sizes[0] / 128;   // 50000 (< 65536 required for u16 ssrc)
    const int E = in_sizes[1];

    char* p = (char*)d_ws;
    auto alloc = [&](size_t bytes) { char* r = p; p += (bytes + 255) & ~(size_t)255; return r; };
    int*      flag  = (int*)alloc(256);
    int*      bsum  = (int*)alloc(256 * 4);
    int*      ro    = (int*)alloc((size_t)(N + 1) * 4);
    ushort_t* ssrc  = (ushort_t*)alloc((size_t)E * 2);         // also aliases cnt (int[N]) early
    ushort_t* hb    = (ushort_t*)alloc((size_t)N * 128 * 2);
    float*    als   = (float*)alloc((size_t)N * 4 * 4);
    float*    ald   = (float*)alloc((size_t)N * 4 * 4);
    ushort_t* xact  = (ushort_t*)alloc((size_t)N * 128 * 2);   // also aliases rank (int[E]) early
    ushort_t* pblk  = (ushort_t*)alloc((size_t)50304 * 2);

    int* cnt  = (int*)ssrc;    // dead once scatter overwrites ssrc
    int* rank = (int*)xact;    // dead once agg0 writes xact

    int g256e4 = (E + 1023) / 1024;
    int g256n = (N + 255) / 256;
    int nb = (N + 1023) / 1024;   // 49 (<= 64 required by wave-scan in k_scan_bc)
    int gg = (N + 63) / 64;
    int gagg = (N + 3) / 4;

    // block 0: dtype sniff; blocks 1..nb: zero cnt (replaces hipMemsetAsync launch)
    k_sniff<<<1 + nb, 256, 0, stream>>>((const uint32*)x, flag, cnt);
    k_f1<<<197 + g256e4, 256, 0, stream>>>(
        d_in[3], d_in[7], d_in[11],
        d_in[4], d_in[8], d_in[12],
        d_in[5], d_in[9], d_in[13],
        d_in[6], d_in[10], d_in[14],
        pblk, flag, dst, cnt, rank, E);
    k_f2<<<nb + gg, 256, 0, stream>>>(cnt, ro, bsum, N, nb,
        x, pblk, hb, als, ald, pblk + 49152, pblk + 49536, N, flag);
    k_scan_bc<<<g256n, 256, 0, stream>>>(ro, bsum, N, nb);
    k_scatter<<<g256e4, 256, 0, stream>>>(src, dst, ro, rank, ssrc, E);

    for (int l = 0; l < 3; l++) {
        const ushort_t* As = pblk + 49152 + l * 128;
        const ushort_t* Ad = pblk + 49536 + l * 128;
        const ushort_t* Bc = pblk + 49920 + l * 128;
        void* outp = (l == 2) ? d_out : (void*)xact;
        if (l > 0) {
            const ushort_t* Wc = pblk + (size_t)l * 16384;
            k_gemm<<<gg, 256, 0, stream>>>(xact, Wc, hb, als, ald, As, Ad, N, flag);
        }
        k_agg<<<gagg, 256, 0, stream>>>(ro, ssrc, hb, als, ald, Bc, outp, N, l < 2 ? 1 : 0,
                                        l == 2 ? 1 : 0, flag);
    }
}